// Round 1
// 422.487 us; speedup vs baseline: 1.0049x; 1.0049x over previous
//
#include <hip/hip_runtime.h>
#include <hip/hip_bf16.h>

#define NN 50000
#define EE 800000
#define IND 128
#define OUTD 64
#define NB 49           // ceil(NN/1024) scan blocks
#define PA_BLOCKS 782   // ceil(NN/64) GEMM blocks
#define DEG_BLOCKS 391  // ceil(EE/2048) deg blocks
#define RH_BLOCKS 6250  // EE*16/2048 r_h-stream blocks (8 float4 per thread)

// ---------------- Front (fused, 3 block ranges) ----------------------------
// [0,782):        z = h@W_fc^T (bf16 out), s1 = z.w1, s2 = z.w2  (VALU-bound)
// [782,1173):     deg/rank count: rank[e] = atomicAdd(&deg[edst[e]],1)
// [1173,7423):    d3[e] = r_h[e]·w3  (204.8 MB HBM stream). 8 independent
//                 float4 loads per thread -> 128 KB in flight per CU at the
//                 LDS-capped 16-wave occupancy; covers HBM latency (was 2
//                 loads -> 18-32 KB in flight -> latency-bound at 1.9 TB/s).
__global__ __launch_bounds__(256) void k_front(
    const float* __restrict__ h, const float* __restrict__ W,
    const float* __restrict__ attn, const int* __restrict__ edst,
    const float* __restrict__ r_h,
    __hip_bfloat16* __restrict__ zb, float* __restrict__ s1,
    float* __restrict__ s2, int* __restrict__ deg, int* __restrict__ rank,
    float* __restrict__ d3) {
  const int tid = threadIdx.x;
  if (blockIdx.x >= PA_BLOCKS + DEG_BLOCKS) {  // ---- r_h·w3 stream
    const int base4 = (blockIdx.x - (PA_BLOCKS + DEG_BLOCKS)) * 2048 + tid;
    const int sub = tid & 15;
    const float4 wv = reinterpret_cast<const float4*>(attn + 2 * OUTD)[sub];
    float4 rv[8];
#pragma unroll
    for (int j = 0; j < 8; ++j)
      rv[j] = reinterpret_cast<const float4*>(r_h)[base4 + j * 256];
    float d[8];
#pragma unroll
    for (int j = 0; j < 8; ++j)
      d[j] = rv[j].x * wv.x + rv[j].y * wv.y + rv[j].z * wv.z + rv[j].w * wv.w;
#pragma unroll
    for (int m = 1; m <= 8; m <<= 1) {
#pragma unroll
      for (int j = 0; j < 8; ++j) d[j] += __shfl_xor(d[j], m, 64);
    }
    if (sub == 0) {
      const int row0 = base4 >> 4;  // = rb*128 + (tid>>4)
#pragma unroll
      for (int j = 0; j < 8; ++j) d3[row0 + 16 * j] = d[j];
    }
    return;
  }
  if (blockIdx.x >= PA_BLOCKS) {  // ---- deg/rank
    const int base = (blockIdx.x - PA_BLOCKS) * 2048 + tid;
#pragma unroll
    for (int j = 0; j < 8; ++j) {
      int e = base + j * 256;
      if (e < EE) rank[e] = atomicAdd(&deg[edst[e]], 1);
    }
    return;
  }
  // ---- GEMM: lane l owns output col l; W[l][:] in 128 VGPRs (LDS-staged);
  // h row broadcast via v_readlane; 4 accumulator chains for FMA-latency ILP.
  __shared__ float Wl[64 * 129];
#pragma unroll
  for (int j = 0; j < 8; ++j) {
    int i4 = tid + j * 256;
    const float4 v = reinterpret_cast<const float4*>(W)[i4];
    int i = i4 * 4;
    int col = i >> 7, k = i & 127;
    float* p = &Wl[col * 129 + k];
    p[0] = v.x; p[1] = v.y; p[2] = v.z; p[3] = v.w;
  }
  __syncthreads();
  const int lane = tid & 63;
  const int wid = tid >> 6;
  float Wreg[128];
#pragma unroll
  for (int k = 0; k < 128; ++k) Wreg[k] = Wl[lane * 129 + k];
  const float w1v = attn[lane];
  const float w2v = attn[64 + lane];
  const int base = blockIdx.x * 64 + wid * 16;
  for (int i = 0; i < 16; ++i) {
    int r = base + i;
    if (r >= NN) return;  // wave-uniform
    const float* hr = h + (size_t)r * IND;
    float h0 = hr[lane];
    float h1 = hr[64 + lane];
    float a0 = 0.f, a1 = 0.f, a2 = 0.f, a3 = 0.f;
#pragma unroll
    for (int k = 0; k < 16; ++k) {
      a0 = fmaf(__uint_as_float(__builtin_amdgcn_readlane(__float_as_uint(h0), 4 * k)),     Wreg[4 * k], a0);
      a1 = fmaf(__uint_as_float(__builtin_amdgcn_readlane(__float_as_uint(h0), 4 * k + 1)), Wreg[4 * k + 1], a1);
      a2 = fmaf(__uint_as_float(__builtin_amdgcn_readlane(__float_as_uint(h0), 4 * k + 2)), Wreg[4 * k + 2], a2);
      a3 = fmaf(__uint_as_float(__builtin_amdgcn_readlane(__float_as_uint(h0), 4 * k + 3)), Wreg[4 * k + 3], a3);
    }
#pragma unroll
    for (int k = 0; k < 16; ++k) {
      a0 = fmaf(__uint_as_float(__builtin_amdgcn_readlane(__float_as_uint(h1), 4 * k)),     Wreg[64 + 4 * k], a0);
      a1 = fmaf(__uint_as_float(__builtin_amdgcn_readlane(__float_as_uint(h1), 4 * k + 1)), Wreg[64 + 4 * k + 1], a1);
      a2 = fmaf(__uint_as_float(__builtin_amdgcn_readlane(__float_as_uint(h1), 4 * k + 2)), Wreg[64 + 4 * k + 2], a2);
      a3 = fmaf(__uint_as_float(__builtin_amdgcn_readlane(__float_as_uint(h1), 4 * k + 3)), Wreg[64 + 4 * k + 3], a3);
    }
    float acc = (a0 + a1) + (a2 + a3);
    zb[(size_t)r * OUTD + lane] = __float2bfloat16(acc);
    float p = acc * w1v, q = acc * w2v;
#pragma unroll
    for (int m = 32; m >= 1; m >>= 1) {
      p += __shfl_xor(p, m, 64);
      q += __shfl_xor(q, m, 64);
    }
    if (lane == 0) { s1[r] = p; s2[r] = q; }
  }
}

// ---------------- Scan: exclusive prefix over deg (CSR offsets) ------------
__global__ __launch_bounds__(1024) void k_scan1(
    const int* __restrict__ deg, int* __restrict__ offL,
    int* __restrict__ blocksum) {
  __shared__ int wsum[16];
  __shared__ int woff[17];
  const int tid = threadIdx.x;
  const int gid = blockIdx.x * 1024 + tid;
  const int lane = tid & 63, wid = tid >> 6;
  int v = (gid < NN) ? deg[gid] : 0;
  int incl = v;
#pragma unroll
  for (int o = 1; o < 64; o <<= 1) {
    int t = __shfl_up(incl, o, 64);
    if (lane >= o) incl += t;
  }
  if (lane == 63) wsum[wid] = incl;
  __syncthreads();
  if (wid == 0 && lane < 16) {
    int s = wsum[lane];
    int si = s;
#pragma unroll
    for (int o = 1; o < 16; o <<= 1) {
      int t = __shfl_up(si, o, 64);
      if (lane >= o) si += t;
    }
    woff[lane] = si - s;
    if (lane == 15) woff[16] = si;
  }
  __syncthreads();
  if (gid < NN) offL[gid] = woff[wid] + incl - v;
  if (tid == 0) blocksum[blockIdx.x] = woff[16];
}

__global__ __launch_bounds__(64) void k_scan2(
    const int* __restrict__ blocksum, int* __restrict__ blockoff) {
  const int lane = threadIdx.x;
  int v = (lane < NB) ? blocksum[lane] : 0;
  int incl = v;
#pragma unroll
  for (int o = 1; o < 64; o <<= 1) {
    int t = __shfl_up(incl, o, 64);
    if (lane >= o) incl += t;
  }
  if (lane < NB) blockoff[lane] = incl - v;
}

// ---------------- Scatter (light): 1 thread/edge ---------------------------
// ee = exp(leaky(s1[src]+s2[dst]+d3[e])); pairs[off[dst]+rank[e]] = (src,ee).
// All inputs coalesced streams or L2-hot 200KB gathers; no r_h traffic.
// No seg_max subtraction: |a| small, exp safe in f32; alpha identical.
__global__ __launch_bounds__(256) void k_scatter(
    const int* __restrict__ esrc, const int* __restrict__ edst,
    const float* __restrict__ d3, const float* __restrict__ s1,
    const float* __restrict__ s2, const int* __restrict__ rank,
    const int* __restrict__ offL, const int* __restrict__ blockoff,
    int2* __restrict__ pairs) {
  const int e = blockIdx.x * 256 + threadIdx.x;
  if (e >= EE) return;
  int s = esrc[e], dd = edst[e];
  float a = s1[s] + s2[dd] + d3[e];
  float el = a > 0.f ? a : 0.01f * a;
  float ex = __expf(el);
  int pos = blockoff[dd >> 10] + offL[dd] + rank[e];
  pairs[pos] = make_int2(s, __float_as_int(ex));
}

// ---------------- Agg: gather per dst node ---------------------------------
// One wave per node. lane = (slot = lane>>4, sub = lane&15): slot indexes
// edges, sub the channel-quad. Gathers bf16 zb rows (128 B); 16 edges per
// mega-iteration -> 8 loads in flight/lane. Loop-weight epilogue also bf16.
__global__ __launch_bounds__(256) void k_agg(
    const __hip_bfloat16* __restrict__ zb, const int2* __restrict__ pairs,
    const int* __restrict__ offL, const int* __restrict__ blockoff,
    const int* __restrict__ deg, const float* __restrict__ LW,
    float* __restrict__ out) {
  const int lane = threadIdx.x & 63, wid = threadIdx.x >> 6;
  const int slot = lane >> 4, sub = lane & 15;
  float4 LWreg[16];  // LW[slot*16+kl][4*sub..4*sub+3]
#pragma unroll
  for (int kl = 0; kl < 16; ++kl)
    LWreg[kl] = reinterpret_cast<const float4*>(LW)[(slot * 16 + kl) * 16 + sub];
  const int r = blockIdx.x * 4 + wid;  // grid exact: 12500*4 = 50000
  const int cnt = deg[r];
  const int2* pp = pairs + (blockoff[r >> 10] + offL[r]);
  float4 acc = make_float4(0.f, 0.f, 0.f, 0.f);
  float wsum = 0.f;
  for (int i = 0; i < cnt; i += 16) {
    int2 p[4];
    float w[4];
#pragma unroll
    for (int j = 0; j < 4; ++j) {
      int e = i + j * 4 + slot;
      bool v = e < cnt;
      p[j] = pp[v ? e : 0];  // pp[0] valid: loop entered => cnt >= 1
      w[j] = v ? __int_as_float(p[j].y) : 0.f;
    }
#pragma unroll
    for (int j = 0; j < 4; ++j) {
      ushort4 uz = reinterpret_cast<const ushort4*>(zb)[(size_t)p[j].x * 16 + sub];
      acc.x = fmaf(w[j], __uint_as_float((unsigned)uz.x << 16), acc.x);
      acc.y = fmaf(w[j], __uint_as_float((unsigned)uz.y << 16), acc.y);
      acc.z = fmaf(w[j], __uint_as_float((unsigned)uz.z << 16), acc.z);
      acc.w = fmaf(w[j], __uint_as_float((unsigned)uz.w << 16), acc.w);
      wsum += w[j];
    }
  }
  // loop-weight partial: k in [slot*16, slot*16+16)
  float4 lacc = make_float4(0.f, 0.f, 0.f, 0.f);
#pragma unroll
  for (int j = 0; j < 4; ++j) {
    ushort4 uz = reinterpret_cast<const ushort4*>(zb)[(size_t)r * 16 + slot * 4 + j];
    float zk[4] = {__uint_as_float((unsigned)uz.x << 16),
                   __uint_as_float((unsigned)uz.y << 16),
                   __uint_as_float((unsigned)uz.z << 16),
                   __uint_as_float((unsigned)uz.w << 16)};
#pragma unroll
    for (int c = 0; c < 4; ++c) {
      float4 lw = LWreg[4 * j + c];
      lacc.x = fmaf(zk[c], lw.x, lacc.x);
      lacc.y = fmaf(zk[c], lw.y, lacc.y);
      lacc.z = fmaf(zk[c], lw.z, lacc.z);
      lacc.w = fmaf(zk[c], lw.w, lacc.w);
    }
  }
  wsum += __shfl_xor(wsum, 16, 64);
  wsum += __shfl_xor(wsum, 32, 64);
  float inv = (cnt > 0) ? 1.f / wsum : 0.f;
  float4 t;
  t.x = fmaf(acc.x, inv, lacc.x);
  t.y = fmaf(acc.y, inv, lacc.y);
  t.z = fmaf(acc.z, inv, lacc.z);
  t.w = fmaf(acc.w, inv, lacc.w);
  t.x += __shfl_xor(t.x, 16, 64); t.x += __shfl_xor(t.x, 32, 64);
  t.y += __shfl_xor(t.y, 16, 64); t.y += __shfl_xor(t.y, 32, 64);
  t.z += __shfl_xor(t.z, 16, 64); t.z += __shfl_xor(t.z, 32, 64);
  t.w += __shfl_xor(t.w, 16, 64); t.w += __shfl_xor(t.w, 32, 64);
  if (slot == 0) {
    float4 res;
    res.x = (cnt > 0 && t.x > 0.f) ? t.x : 0.f;
    res.y = (cnt > 0 && t.y > 0.f) ? t.y : 0.f;
    res.z = (cnt > 0 && t.z > 0.f) ? t.z : 0.f;
    res.w = (cnt > 0 && t.w > 0.f) ? t.w : 0.f;
    reinterpret_cast<float4*>(out)[(size_t)r * 16 + sub] = res;
  }
}

extern "C" void kernel_launch(void* const* d_in, const int* in_sizes, int n_in,
                              void* d_out, int out_size, void* d_ws, size_t ws_size,
                              hipStream_t stream) {
  const float* h    = (const float*)d_in[0];  // [N,128]
  const float* r_h  = (const float*)d_in[1];  // [E,64]
  const float* W_fc = (const float*)d_in[2];  // [64,128]
  const float* attn = (const float*)d_in[3];  // [1,192]
  const float* LW   = (const float*)d_in[4];  // [64,64]
  const int* esrc   = (const int*)d_in[5];    // [E]
  const int* edst   = (const int*)d_in[6];    // [E]
  float* out = (float*)d_out;                 // [N,64]

  char* ws = (char*)d_ws;
  __hip_bfloat16* zb = (__hip_bfloat16*)(ws);  //  6,400,000 B
  int2*  pairs = (int2*)(ws + 6400000);        //  6,400,000 B
  int*   rank  = (int*)(ws + 12800000);        //  3,200,000 B
  float* d3    = (float*)(ws + 16000000);      //  3,200,000 B
  float* s1    = (float*)(ws + 19200000);      //    200,000 B
  float* s2    = (float*)(ws + 19400000);      //    200,000 B
  int*   deg   = (int*)(ws + 19600000);        //    200,000 B
  int*   offL  = (int*)(ws + 19800000);        //    200,000 B
  int*   bsum  = (int*)(ws + 20000000);        //        256 B
  int*   boff  = (int*)(ws + 20001024);        //        256 B
  // total ws use ~20 MB

  hipMemsetAsync(deg, 0, (size_t)NN * sizeof(int), stream);

  k_front<<<PA_BLOCKS + DEG_BLOCKS + RH_BLOCKS, 256, 0, stream>>>(
      h, W_fc, attn, edst, r_h, zb, s1, s2, deg, rank, d3);
  k_scan1<<<NB, 1024, 0, stream>>>(deg, offL, bsum);
  k_scan2<<<1, 64, 0, stream>>>(bsum, boff);
  k_scatter<<<(EE + 255) / 256, 256, 0, stream>>>(
      esrc, edst, d3, s1, s2, rank, offL, boff, pairs);
  k_agg<<<NN / 4, 256, 0, stream>>>(zb, pairs, offL, boff, deg, LW, out);
}